// Round 5
// baseline (185.944 us; speedup 1.0000x reference)
//
#include <hip/hip_runtime.h>

#define DIM    256
#define NCODES 1024
#define BATCH  16
#define SEQ    2048
#define NROWS  (BATCH * SEQ)   // 32768
#define NTHR   256
#define NGRP   16              // 16 ng tiles of 64 codes

typedef short short8 __attribute__((ext_vector_type(8)));
typedef float f32x4 __attribute__((ext_vector_type(4)));

__device__ __forceinline__ float wave_reduce_sum(float s) {
#pragma unroll
  for (int off = 32; off > 0; off >>= 1) s += __shfl_down(s, off, 64);
  return s;
}

// round-to-nearest-even float -> bf16 (raw short)
__device__ __forceinline__ short f2bf(float f) {
  unsigned u = __builtin_bit_cast(unsigned, f);
  u = (u + 0x7fff + ((u >> 16) & 1)) >> 16;
  return (short)u;
}
__device__ __forceinline__ float bf2f(short s) {
  unsigned u = ((unsigned)(unsigned short)s) << 16;
  return __builtin_bit_cast(float, u);
}

// ---- prep A: feat [32768][256] f32 -> abuf fragment-major bf16, packed [xh|xl] (512 k')
// abuf short8 index: rb16*1024 + kg*16 + m   (rb16=row>>4, m=row&15, kg in [0,64))
// kg in [0,32): xh(k=kg*8+j) ; kg in [32,64): xl(k=(kg-32)*8+j)
__global__ __launch_bounds__(NTHR) void k_prepA(const float* __restrict__ feat,
                                                short8* __restrict__ abuf) {
  const int rb = blockIdx.x;   // 2048 blocks of 16 rows
  const int t = threadIdx.x;
  __shared__ float tile[16 * 257];  // +1 pad: conflict-free
  const float* src = feat + (size_t)rb * 16 * DIM;
#pragma unroll
  for (int i = 0; i < 16; ++i) tile[i * 257 + t] = src[i * DIM + t];
  __syncthreads();
#pragma unroll
  for (int it = 0; it < 4; ++it) {
    const int idx = it * NTHR + t;   // 1024 items = 64 kg x 16 m
    const int kg = idx >> 4;
    const int m = idx & 15;
    const int region = kg >> 5;      // 0:xh 1:xl
    const int k0 = (kg & 31) * 8;
    short8 v;
#pragma unroll
    for (int j = 0; j < 8; ++j) {
      const float x = tile[m * 257 + k0 + j];
      const short h = f2bf(x);
      v[j] = region ? f2bf(x - bf2f(h)) : h;
    }
    abuf[(size_t)rb * 1024 + idx] = v;
  }
}

// ---- prep B: codebook [1024][256] f32 -> bbuf packed [wh|wl] + cbsq ----
__global__ __launch_bounds__(NTHR) void k_prepB(const float* __restrict__ cb,
                                                short8* __restrict__ bbuf,
                                                float* __restrict__ cbsq) {
  const int nb = blockIdx.x;   // 64 blocks of 16 codes
  const int t = threadIdx.x;
  __shared__ float tile[16 * 257];
  const float* src = cb + (size_t)nb * 16 * DIM;
#pragma unroll
  for (int i = 0; i < 16; ++i) tile[i * 257 + t] = src[i * DIM + t];
  __syncthreads();
#pragma unroll
  for (int it = 0; it < 4; ++it) {
    const int idx = it * NTHR + t;
    const int kg = idx >> 4;
    const int m = idx & 15;
    const int region = kg >> 5;
    const int k0 = (kg & 31) * 8;
    short8 v;
#pragma unroll
    for (int j = 0; j < 8; ++j) {
      const float w = tile[m * 257 + k0 + j];
      const short h = f2bf(w);
      v[j] = region ? f2bf(w - bf2f(h)) : h;
    }
    bbuf[(size_t)nb * 1024 + idx] = v;
  }
  if (t < 16) {
    float s = 0.f;
    for (int c = 0; c < DIM; ++c) { const float w = tile[t * 257 + c]; s = fmaf(w, w, s); }
    cbsq[nb * 16 + t] = s;
  }
}

// ---- denom + zero loss accumulators ----
__global__ __launch_bounds__(NTHR) void k_mask(const float* __restrict__ mask,
                                               float* __restrict__ denom,
                                               float* __restrict__ lsum) {
  const int b = blockIdx.x;
  const int t = threadIdx.x;
  float s = 0.f;
  for (int i = t; i < SEQ; i += NTHR) s += mask[b * SEQ + i];
  s = wave_reduce_sum(s);
  __shared__ float red[NTHR / 64];
  if ((t & 63) == 0) red[t >> 6] = s;
  __syncthreads();
  if (t == 0) { denom[b] = red[0] + red[1] + red[2] + red[3]; lsum[b] = 0.f; }
}

// ---- barrier-free MFMA score + partial argmin, chunked 3-product K-loop ----
// Wave tile: 64 rows x 64 codes. 8 chunks of k=32; per chunk load
// a_hi/a_lo/b_hi/b_lo once (16 loads) and fire hh, lh, hl (48 MFMAs).
// Block = 4 waves = 2 rg x 2 ng; per-chunk block working set = 32 KB -> L1.
__global__ __launch_bounds__(NTHR, 3) void k_score(const short8* __restrict__ abuf,
                                                   const short8* __restrict__ bbuf,
                                                   const float* __restrict__ cbsq,
                                                   float* __restrict__ pdist,
                                                   int* __restrict__ pidx) {
  const int t = threadIdx.x;
  const int w = t >> 6;
  const int lane = t & 63;
  const int l15 = lane & 15;
  const int quad = lane >> 4;
  const int by = blockIdx.x & 255;   // rg-pair: XCD striping via blockIdx%8
  const int bx = blockIdx.x >> 8;    // ng-pair
  const int rg = by * 2 + (w >> 1);  // [0,512): 64-row group
  const int ng = bx * 2 + (w & 1);   // [0,16):  64-code group

  const short8* __restrict__ Ap = abuf + (size_t)rg * 4096 + quad * 16 + l15;
  const short8* __restrict__ Bp = bbuf + (size_t)ng * 4096 + quad * 16 + l15;

  f32x4 C[4][4];
#pragma unroll
  for (int mi = 0; mi < 4; ++mi)
#pragma unroll
    for (int ni = 0; ni < 4; ++ni) C[mi][ni] = (f32x4)0.f;

#pragma unroll 2
  for (int s = 0; s < 8; ++s) {
    const int kh = s * 64;        // hi fragments (kg = s*4+quad)
    const int kl = kh + 512;      // lo fragments (kg = 32 + s*4+quad)
    short8 ah[4], bh[4], al[4], bl[4];
#pragma unroll
    for (int mi = 0; mi < 4; ++mi) ah[mi] = Ap[mi * 1024 + kh];
#pragma unroll
    for (int ni = 0; ni < 4; ++ni) bh[ni] = Bp[ni * 1024 + kh];
#pragma unroll
    for (int mi = 0; mi < 4; ++mi) al[mi] = Ap[mi * 1024 + kl];
#pragma unroll
    for (int ni = 0; ni < 4; ++ni) bl[ni] = Bp[ni * 1024 + kl];
    // xh.wh
#pragma unroll
    for (int mi = 0; mi < 4; ++mi)
#pragma unroll
      for (int ni = 0; ni < 4; ++ni)
        C[mi][ni] = __builtin_amdgcn_mfma_f32_16x16x32_bf16(ah[mi], bh[ni], C[mi][ni], 0, 0, 0);
    // xl.wh
#pragma unroll
    for (int mi = 0; mi < 4; ++mi)
#pragma unroll
      for (int ni = 0; ni < 4; ++ni)
        C[mi][ni] = __builtin_amdgcn_mfma_f32_16x16x32_bf16(al[mi], bh[ni], C[mi][ni], 0, 0, 0);
    // xh.wl
#pragma unroll
    for (int mi = 0; mi < 4; ++mi)
#pragma unroll
      for (int ni = 0; ni < 4; ++ni)
        C[mi][ni] = __builtin_amdgcn_mfma_f32_16x16x32_bf16(ah[mi], bl[ni], C[mi][ni], 0, 0, 0);
  }

  float cs[4];
#pragma unroll
  for (int ni = 0; ni < 4; ++ni) cs[ni] = cbsq[ng * 64 + ni * 16 + l15];

  float best[16];
  int bidx[16];
#pragma unroll
  for (int mi = 0; mi < 4; ++mi)
#pragma unroll
    for (int r = 0; r < 4; ++r) {
      float bd = 3.4e38f;
      int bi = 0;
#pragma unroll
      for (int ni = 0; ni < 4; ++ni) {
        const float d = fmaf(-2.f, C[mi][ni][r], cs[ni]);
        const int code = ng * 64 + ni * 16 + l15;
        if (d < bd) { bd = d; bi = code; }
      }
      best[mi * 4 + r] = bd;
      bidx[mi * 4 + r] = bi;
    }
#pragma unroll
  for (int m = 1; m <= 8; m <<= 1) {
#pragma unroll
    for (int j = 0; j < 16; ++j) {
      const float od = __shfl_xor(best[j], m, 64);
      const int oi = __shfl_xor(bidx[j], m, 64);
      if (od < best[j] || (od == best[j] && oi < bidx[j])) { best[j] = od; bidx[j] = oi; }
    }
  }
  if (l15 == 0) {
#pragma unroll
    for (int mi = 0; mi < 4; ++mi)
#pragma unroll
      for (int r = 0; r < 4; ++r) {
        const int row = rg * 64 + mi * 16 + quad * 4 + r;
        pdist[row * NGRP + ng] = best[mi * 4 + r];
        pidx[row * NGRP + ng] = bidx[mi * 4 + r];
      }
  }
}

// ---- fused merge + gather + straight-through out + masked MSE ----
__global__ __launch_bounds__(NTHR) void k_gather(const float* __restrict__ feat,
                                                 const float* __restrict__ cb,
                                                 const float* __restrict__ mask,
                                                 const float* __restrict__ pdist,
                                                 const int* __restrict__ pidx,
                                                 float* __restrict__ outq,
                                                 float* __restrict__ lsum) {
  const int t = threadIdx.x;
  const int row0 = blockIdx.x * 64;
  __shared__ float sd[NTHR];
  __shared__ int si[NTHR];
  __shared__ int skid[64];
  {
    const float4 pd = ((const float4*)pdist)[row0 * 4 + t];
    const int4 pi = ((const int4*)pidx)[row0 * 4 + t];
    float bd = pd.x; int bi = pi.x;
    if (pd.y < bd || (pd.y == bd && pi.y < bi)) { bd = pd.y; bi = pi.y; }
    if (pd.z < bd || (pd.z == bd && pi.z < bi)) { bd = pd.z; bi = pi.z; }
    if (pd.w < bd || (pd.w == bd && pi.w < bi)) { bd = pd.w; bi = pi.w; }
    sd[t] = bd; si[t] = bi;
  }
  __syncthreads();
  if (t < 64) {
    float bd = sd[t * 4]; int bi = si[t * 4];
#pragma unroll
    for (int j = 1; j < 4; ++j) {
      const float od = sd[t * 4 + j]; const int oi = si[t * 4 + j];
      if (od < bd || (od == bd && oi < bi)) { bd = od; bi = oi; }
    }
    skid[t] = bi;
  }
  __syncthreads();
  const int wv = t >> 6;
  const int dg = t & 63;
  const int b = row0 >> 11;
  float acc = 0.f;
#pragma unroll
  for (int i = 0; i < 16; ++i) {
    const int r = wv * 16 + i;
    const size_t row = row0 + r;
    const int k = skid[r];
    const float4 q = ((const float4*)cb)[k * (DIM / 4) + dg];
    const float4 x = ((const float4*)feat)[row * (DIM / 4) + dg];
    float4 o;
    o.x = x.x + (q.x - x.x);
    o.y = x.y + (q.y - x.y);
    o.z = x.z + (q.z - x.z);
    o.w = x.w + (q.w - x.w);
    ((float4*)outq)[row * (DIM / 4) + dg] = o;
    const float m = mask[row];
    const float dx = x.x - q.x, dy = x.y - q.y, dz = x.z - q.z, dw = x.w - q.w;
    acc = fmaf(m, dx * dx + dy * dy + dz * dz + dw * dw, acc);
  }
  acc = wave_reduce_sum(acc);
  __shared__ float red[4];
  if ((t & 63) == 0) red[wv] = acc;
  __syncthreads();
  if (t == 0) atomicAdd(&lsum[b], red[0] + red[1] + red[2] + red[3]);
}

__global__ void k_final(const float* __restrict__ lsum,
                        const float* __restrict__ denom,
                        float* __restrict__ outl) {
  const int t = threadIdx.x;
  if (t < BATCH) {
    const float v = lsum[t] / denom[t];
    outl[t] = v;          // quant_loss
    outl[BATCH + t] = v;  // commit_loss (identical in forward)
  }
}

extern "C" void kernel_launch(void* const* d_in, const int* in_sizes, int n_in,
                              void* d_out, int out_size, void* d_ws, size_t ws_size,
                              hipStream_t stream) {
  const float* feat = (const float*)d_in[0];  // [16,2048,256]
  const float* mask = (const float*)d_in[1];  // [16,2048]
  const float* cb   = (const float*)d_in[2];  // [1024,256]
  float* out = (float*)d_out;

  char* p = (char*)d_ws;
  short8* abuf = (short8*)p;                 p += (size_t)NROWS * 512 * 2;   // 33.55 MB
  short8* bbuf = (short8*)p;                 p += (size_t)NCODES * 512 * 2;  // 1.05 MB
  float* cbsq  = (float*)p;                  p += NCODES * 4;
  float* pdist = (float*)p;                  p += (size_t)NROWS * NGRP * 4;  // 2 MB
  int*   pidx  = (int*)p;                    p += (size_t)NROWS * NGRP * 4;  // 2 MB
  float* denom = (float*)p;                  p += BATCH * 4;
  float* lsum  = (float*)p;

  k_prepA<<<NROWS / 16, NTHR, 0, stream>>>(feat, abuf);
  k_prepB<<<NCODES / 16, NTHR, 0, stream>>>(cb, bbuf, cbsq);
  k_mask<<<BATCH, NTHR, 0, stream>>>(mask, denom, lsum);
  k_score<<<2048, NTHR, 0, stream>>>(abuf, bbuf, cbsq, pdist, pidx);
  k_gather<<<NROWS / 64, NTHR, 0, stream>>>(feat, cb, mask, pdist, pidx, out, lsum);
  k_final<<<1, 64, 0, stream>>>(lsum, denom, out + (size_t)NROWS * DIM);
}

// Round 6
// 169.645 us; speedup vs baseline: 1.0961x; 1.0961x over previous
//
#include <hip/hip_runtime.h>

#define DIM    256
#define NCODES 1024
#define BATCH  16
#define SEQ    2048
#define NROWS  (BATCH * SEQ)   // 32768
#define NTHR   256
#define NGRP   16              // 16 ng tiles of 64 codes

typedef short short8 __attribute__((ext_vector_type(8)));
typedef float f32x4 __attribute__((ext_vector_type(4)));

__device__ __forceinline__ float wave_reduce_sum(float s) {
#pragma unroll
  for (int off = 32; off > 0; off >>= 1) s += __shfl_down(s, off, 64);
  return s;
}

// round-to-nearest-even float -> bf16 (raw short)
__device__ __forceinline__ short f2bf(float f) {
  unsigned u = __builtin_bit_cast(unsigned, f);
  u = (u + 0x7fff + ((u >> 16) & 1)) >> 16;
  return (short)u;
}
__device__ __forceinline__ float bf2f(short s) {
  unsigned u = ((unsigned)(unsigned short)s) << 16;
  return __builtin_bit_cast(float, u);
}

// ---- prep B: codebook [1024][256] f32 -> bbuf packed [wh|wl] + cbsq ----
// bbuf short8 index: nb16*1024 + kg*16 + m ; kg in [0,32): wh ; [32,64): wl
__global__ __launch_bounds__(NTHR) void k_prepB(const float* __restrict__ cb,
                                                short8* __restrict__ bbuf,
                                                float* __restrict__ cbsq) {
  const int nb = blockIdx.x;   // 64 blocks of 16 codes
  const int t = threadIdx.x;
  __shared__ float tile[16 * 257];
  const float* src = cb + (size_t)nb * 16 * DIM;
#pragma unroll
  for (int i = 0; i < 16; ++i) tile[i * 257 + t] = src[i * DIM + t];
  __syncthreads();
#pragma unroll
  for (int it = 0; it < 4; ++it) {
    const int idx = it * NTHR + t;
    const int kg = idx >> 4;
    const int m = idx & 15;
    const int region = kg >> 5;
    const int k0 = (kg & 31) * 8;
    short8 v;
#pragma unroll
    for (int j = 0; j < 8; ++j) {
      const float w = tile[m * 257 + k0 + j];
      const short h = f2bf(w);
      v[j] = region ? f2bf(w - bf2f(h)) : h;
    }
    bbuf[(size_t)nb * 1024 + idx] = v;
  }
  if (t < 16) {
    float s = 0.f;
    for (int c = 0; c < DIM; ++c) { const float w = tile[t * 257 + c]; s = fmaf(w, w, s); }
    cbsq[nb * 16 + t] = s;
  }
}

// ---- denom + zero loss accumulators ----
__global__ __launch_bounds__(NTHR) void k_mask(const float* __restrict__ mask,
                                               float* __restrict__ denom,
                                               float* __restrict__ lsum) {
  const int b = blockIdx.x;
  const int t = threadIdx.x;
  float s = 0.f;
  for (int i = t; i < SEQ; i += NTHR) s += mask[b * SEQ + i];
  s = wave_reduce_sum(s);
  __shared__ float red[NTHR / 64];
  if ((t & 63) == 0) red[t >> 6] = s;
  __syncthreads();
  if (t == 0) { denom[b] = red[0] + red[1] + red[2] + red[3]; lsum[b] = 0.f; }
}

// ---- fused convert + LDS-staged MFMA score + partial argmin ----
// Block tile: 128 rows x 128 codes. blockIdx = rowTile*8 + codeTile.
// K-loop: 8 chunks of k=32. Per chunk:
//   stage A: feat f32 -> hi/lo bf16 -> LDS [rb16l(8)][reg(2)][kgl(4)][m(16)] short8
//   stage B: bbuf 1KB runs -> LDS   [nb16l(8)][reg(2)][kgl(4)][m(16)] short8
//   compute: pure ds_read_b128 + 48 MFMAs/wave (hh, lh, hl).
__global__ __launch_bounds__(NTHR, 3) void k_score(const float* __restrict__ feat,
                                                   const short8* __restrict__ bbuf,
                                                   const float* __restrict__ cbsq,
                                                   float* __restrict__ pdist,
                                                   int* __restrict__ pidx) {
  __shared__ short8 sA[1024];  // 16 KB
  __shared__ short8 sB[1024];  // 16 KB
  const int t = threadIdx.x;
  const int w = t >> 6;
  const int lane = t & 63;
  const int l15 = lane & 15;
  const int quad = lane >> 4;
  const int R = blockIdx.x >> 3;    // rowTile [0,256): rows R*128..
  const int Ncd = blockIdx.x & 7;   // codeTile [0,8): codes Ncd*128.. ; XCD round-robin
  const int h = w >> 1;             // row half
  const int c = w & 1;              // code half

  f32x4 C[4][4];
#pragma unroll
  for (int mi = 0; mi < 4; ++mi)
#pragma unroll
    for (int ni = 0; ni < 4; ++ni) C[mi][ni] = (f32x4)0.f;

  const float4* __restrict__ fsrc = (const float4*)feat;
  const int nb0 = Ncd * 8;

  for (int s = 0; s < 8; ++s) {
    __syncthreads();  // previous iteration's readers done
    // ---- stage A: 512 items; item a: row_local=a>>2, kgl=a&3 ----
#pragma unroll
    for (int i = 0; i < 2; ++i) {
      const int a = i * NTHR + t;
      const int rl = a >> 2;          // row_local [0,128)
      const int kgl = a & 3;
      const size_t f4 = ((size_t)R * 128 + rl) * 64 + s * 8 + kgl * 2;
      const float4 x0 = fsrc[f4];
      const float4 x1 = fsrc[f4 + 1];
      const float xs[8] = {x0.x, x0.y, x0.z, x0.w, x1.x, x1.y, x1.z, x1.w};
      short8 hi, lo;
#pragma unroll
      for (int j = 0; j < 8; ++j) {
        const short hh = f2bf(xs[j]);
        hi[j] = hh;
        lo[j] = f2bf(xs[j] - bf2f(hh));
      }
      const int rb16l = rl >> 4, m = rl & 15;
      sA[((rb16l * 2 + 0) * 4 + kgl) * 16 + m] = hi;
      sA[((rb16l * 2 + 1) * 4 + kgl) * 16 + m] = lo;
    }
    // ---- stage B: 1024 items; id: [nb16l(3)][reg(1)][kgl(2)][m(4)] ----
#pragma unroll
    for (int i = 0; i < 4; ++i) {
      const int id = i * NTHR + t;
      const int nb16l = id >> 7;
      const int reg = (id >> 6) & 1;
      const int kgl = (id >> 4) & 3;
      const int m = id & 15;
      sB[id] = bbuf[(size_t)(nb0 + nb16l) * 1024 + (reg * 32 + s * 4 + kgl) * 16 + m];
    }
    __syncthreads();
    // ---- compute: frags from LDS, 48 MFMAs ----
    short8 ah[4], al[4], bh[4], bl[4];
#pragma unroll
    for (int mi = 0; mi < 4; ++mi) {
      ah[mi] = sA[((h * 4 + mi) * 2 + 0) * 64 + quad * 16 + l15];
      al[mi] = sA[((h * 4 + mi) * 2 + 1) * 64 + quad * 16 + l15];
    }
#pragma unroll
    for (int ni = 0; ni < 4; ++ni) {
      bh[ni] = sB[((c * 4 + ni) * 2 + 0) * 64 + quad * 16 + l15];
      bl[ni] = sB[((c * 4 + ni) * 2 + 1) * 64 + quad * 16 + l15];
    }
#pragma unroll
    for (int mi = 0; mi < 4; ++mi)
#pragma unroll
      for (int ni = 0; ni < 4; ++ni)
        C[mi][ni] = __builtin_amdgcn_mfma_f32_16x16x32_bf16(ah[mi], bh[ni], C[mi][ni], 0, 0, 0);
#pragma unroll
    for (int mi = 0; mi < 4; ++mi)
#pragma unroll
      for (int ni = 0; ni < 4; ++ni)
        C[mi][ni] = __builtin_amdgcn_mfma_f32_16x16x32_bf16(al[mi], bh[ni], C[mi][ni], 0, 0, 0);
#pragma unroll
    for (int mi = 0; mi < 4; ++mi)
#pragma unroll
      for (int ni = 0; ni < 4; ++ni)
        C[mi][ni] = __builtin_amdgcn_mfma_f32_16x16x32_bf16(ah[mi], bl[ni], C[mi][ni], 0, 0, 0);
  }

  // ---- epilogue: dist = cbsq - 2*dot, per-lane then cross-lane argmin ----
  float cs[4];
#pragma unroll
  for (int ni = 0; ni < 4; ++ni) cs[ni] = cbsq[Ncd * 128 + c * 64 + ni * 16 + l15];

  float best[16];
  int bidx[16];
#pragma unroll
  for (int mi = 0; mi < 4; ++mi)
#pragma unroll
    for (int r = 0; r < 4; ++r) {
      float bd = 3.4e38f;
      int bi = 0;
#pragma unroll
      for (int ni = 0; ni < 4; ++ni) {
        const float d = fmaf(-2.f, C[mi][ni][r], cs[ni]);
        const int code = Ncd * 128 + c * 64 + ni * 16 + l15;
        if (d < bd) { bd = d; bi = code; }
      }
      best[mi * 4 + r] = bd;
      bidx[mi * 4 + r] = bi;
    }
#pragma unroll
  for (int m = 1; m <= 8; m <<= 1) {
#pragma unroll
    for (int j = 0; j < 16; ++j) {
      const float od = __shfl_xor(best[j], m, 64);
      const int oi = __shfl_xor(bidx[j], m, 64);
      if (od < best[j] || (od == best[j] && oi < bidx[j])) { best[j] = od; bidx[j] = oi; }
    }
  }
  if (l15 == 0) {
    const int ng = Ncd * 2 + c;
#pragma unroll
    for (int mi = 0; mi < 4; ++mi)
#pragma unroll
      for (int r = 0; r < 4; ++r) {
        const int row = R * 128 + h * 64 + mi * 16 + quad * 4 + r;
        pdist[row * NGRP + ng] = best[mi * 4 + r];
        pidx[row * NGRP + ng] = bidx[mi * 4 + r];
      }
  }
}

// ---- fused merge + gather + straight-through out + masked MSE ----
__global__ __launch_bounds__(NTHR) void k_gather(const float* __restrict__ feat,
                                                 const float* __restrict__ cb,
                                                 const float* __restrict__ mask,
                                                 const float* __restrict__ pdist,
                                                 const int* __restrict__ pidx,
                                                 float* __restrict__ outq,
                                                 float* __restrict__ lsum) {
  const int t = threadIdx.x;
  const int row0 = blockIdx.x * 64;
  __shared__ float sd[NTHR];
  __shared__ int si[NTHR];
  __shared__ int skid[64];
  {
    const float4 pd = ((const float4*)pdist)[row0 * 4 + t];
    const int4 pi = ((const int4*)pidx)[row0 * 4 + t];
    float bd = pd.x; int bi = pi.x;
    if (pd.y < bd || (pd.y == bd && pi.y < bi)) { bd = pd.y; bi = pi.y; }
    if (pd.z < bd || (pd.z == bd && pi.z < bi)) { bd = pd.z; bi = pi.z; }
    if (pd.w < bd || (pd.w == bd && pi.w < bi)) { bd = pd.w; bi = pi.w; }
    sd[t] = bd; si[t] = bi;
  }
  __syncthreads();
  if (t < 64) {
    float bd = sd[t * 4]; int bi = si[t * 4];
#pragma unroll
    for (int j = 1; j < 4; ++j) {
      const float od = sd[t * 4 + j]; const int oi = si[t * 4 + j];
      if (od < bd || (od == bd && oi < bi)) { bd = od; bi = oi; }
    }
    skid[t] = bi;
  }
  __syncthreads();
  const int wv = t >> 6;
  const int dg = t & 63;
  const int b = row0 >> 11;
  float acc = 0.f;
#pragma unroll
  for (int i = 0; i < 16; ++i) {
    const int r = wv * 16 + i;
    const size_t row = row0 + r;
    const int k = skid[r];
    const float4 q = ((const float4*)cb)[k * (DIM / 4) + dg];
    const float4 x = ((const float4*)feat)[row * (DIM / 4) + dg];
    float4 o;
    o.x = x.x + (q.x - x.x);
    o.y = x.y + (q.y - x.y);
    o.z = x.z + (q.z - x.z);
    o.w = x.w + (q.w - x.w);
    ((float4*)outq)[row * (DIM / 4) + dg] = o;
    const float m = mask[row];
    const float dx = x.x - q.x, dy = x.y - q.y, dz = x.z - q.z, dw = x.w - q.w;
    acc = fmaf(m, dx * dx + dy * dy + dz * dz + dw * dw, acc);
  }
  acc = wave_reduce_sum(acc);
  __shared__ float red[4];
  if ((t & 63) == 0) red[wv] = acc;
  __syncthreads();
  if (t == 0) atomicAdd(&lsum[b], red[0] + red[1] + red[2] + red[3]);
}

__global__ void k_final(const float* __restrict__ lsum,
                        const float* __restrict__ denom,
                        float* __restrict__ outl) {
  const int t = threadIdx.x;
  if (t < BATCH) {
    const float v = lsum[t] / denom[t];
    outl[t] = v;          // quant_loss
    outl[BATCH + t] = v;  // commit_loss (identical in forward)
  }
}

extern "C" void kernel_launch(void* const* d_in, const int* in_sizes, int n_in,
                              void* d_out, int out_size, void* d_ws, size_t ws_size,
                              hipStream_t stream) {
  const float* feat = (const float*)d_in[0];  // [16,2048,256]
  const float* mask = (const float*)d_in[1];  // [16,2048]
  const float* cb   = (const float*)d_in[2];  // [1024,256]
  float* out = (float*)d_out;

  char* p = (char*)d_ws;
  short8* bbuf = (short8*)p;                 p += (size_t)NCODES * 512 * 2;  // 1.05 MB
  float* cbsq  = (float*)p;                  p += NCODES * 4;
  float* pdist = (float*)p;                  p += (size_t)NROWS * NGRP * 4;  // 2 MB
  int*   pidx  = (int*)p;                    p += (size_t)NROWS * NGRP * 4;  // 2 MB
  float* denom = (float*)p;                  p += BATCH * 4;
  float* lsum  = (float*)p;

  k_prepB<<<NCODES / 16, NTHR, 0, stream>>>(cb, bbuf, cbsq);
  k_mask<<<BATCH, NTHR, 0, stream>>>(mask, denom, lsum);
  k_score<<<2048, NTHR, 0, stream>>>(feat, bbuf, cbsq, pdist, pidx);
  k_gather<<<NROWS / 64, NTHR, 0, stream>>>(feat, cb, mask, pdist, pidx, out, lsum);
  k_final<<<1, 64, 0, stream>>>(lsum, denom, out + (size_t)NROWS * DIM);
}